// Round 9
// baseline (256.849 us; speedup 1.0000x reference)
//
#include <hip/hip_runtime.h>

// DNNF fused pipeline for MI355X (gfx950). R9 = R4 core (proven best K-loop:
// BK=64 double-buffer, vmcnt(10)/lgkm(0) barriers, R4 grid) + new wave-local
// epilogue: each wave reduces its OWN 64x96 acc tile via a bf16-packed
// two-rows-per-u32 LDS region ([96][36] u32 per wave) -> 24 ds_write_b64 +
// 48 ds_read_b32 per thread (was 96+48 b32 with 6 barriers), ZERO epilogue
// barriers. R5 grid swizzle reverted (it cost +25 us despite 7x less fetch).

#define BATCH 8192
#define IDIM 512
#define NFORM 256
#define NLIT 10752
#define WT_ROWS 11136  // NLIT + 256 mu + 128 zero pad; /192 = 58 tiles

#define BM 128
#define BN 192
#define BK 64
#define BUFB 40960  // one LDS buffer: A 16384 B + B 24576 B
#define PADU 36     // u32 row pitch of packed-lit region: even (b64 align),
                    // 4*c+rp bank map -> reads all-distinct, writes 2-way

typedef __bf16 bf16x8 __attribute__((ext_vector_type(8)));
typedef float f32x4 __attribute__((ext_vector_type(4)));
typedef unsigned short u16;
typedef unsigned int u32;

__device__ __forceinline__ u16 f2bf(float f) {
  u32 u = __float_as_uint(f);
  u = (u + 0x7fffu + ((u >> 16) & 1u)) >> 16;  // RNE
  return (u16)u;
}

__device__ __forceinline__ float fast_tanh(float x) {
  float e = __expf(2.0f * x);
  return 1.0f - 2.0f * __builtin_amdgcn_rcpf(e + 1.0f);
}

__device__ __forceinline__ void async_cp16(const void* g, void* l) {
  __builtin_amdgcn_global_load_lds(
      (const u32 __attribute__((address_space(1)))*)g,
      (u32 __attribute__((address_space(3)))*)l, 16, 0, 0);
}

// ---------------- fused prep (one dispatch) ----------------

#define PREPX_BLKS 2048
#define PREPW_BLKS 1344  // 168 l-tiles x 8 k-tiles

__global__ __launch_bounds__(256) void prep_all(
    const float* __restrict__ x, const float* __restrict__ W,
    const float* __restrict__ M, const float* __restrict__ mu,
    u16* __restrict__ xb, u16* __restrict__ wt, float* __restrict__ xsq,
    float* __restrict__ musq, float* __restrict__ form_sum) {
  __shared__ float lds[64 * 65];  // 16.6 KB; also reused as red[256]
  const int blk = blockIdx.x, tid = threadIdx.x;

  if (blk < PREPX_BLKS) {
    ((uint4*)form_sum)[blk * 256 + tid] = make_uint4(0, 0, 0, 0);
    int wave = tid >> 6, lane = tid & 63;
    int row = blk * 4 + wave;
    const float4* px = (const float4*)(x + (size_t)row * IDIM);
    float4 a = px[lane * 2], b = px[lane * 2 + 1];
    uint4 pk;
    pk.x = (u32)f2bf(a.x) | ((u32)f2bf(a.y) << 16);
    pk.y = (u32)f2bf(a.z) | ((u32)f2bf(a.w) << 16);
    pk.z = (u32)f2bf(b.x) | ((u32)f2bf(b.y) << 16);
    pk.w = (u32)f2bf(b.z) | ((u32)f2bf(b.w) << 16);
    ((uint4*)(xb + (size_t)row * IDIM))[lane] = pk;
    float s = a.x * a.x + a.y * a.y + a.z * a.z + a.w * a.w +
              b.x * b.x + b.y * b.y + b.z * b.z + b.w * b.w;
#pragma unroll
    for (int o = 32; o > 0; o >>= 1) s += __shfl_down(s, o);
    if (lane == 0) xsq[row] = s;
  } else if (blk < PREPX_BLKS + PREPW_BLKS) {
    int b = blk - PREPX_BLKS;
    int l0 = (b % 168) * 64, k0 = (b / 168) * 64;
#pragma unroll
    for (int j = 0; j < 4; ++j) {
      int idx = tid + j * 256;
      int kk = idx >> 4, l4 = idx & 15;
      size_t g = (size_t)(k0 + kk) * NLIT + l0 + l4 * 4;
      float4 w4 = *(const float4*)(W + g);
      float4 m4 = *(const float4*)(M + g);
      lds[kk * 65 + l4 * 4 + 0] = w4.x * m4.x;
      lds[kk * 65 + l4 * 4 + 1] = w4.y * m4.y;
      lds[kk * 65 + l4 * 4 + 2] = w4.z * m4.z;
      lds[kk * 65 + l4 * 4 + 3] = w4.w * m4.w;
    }
    __syncthreads();
    int l = tid >> 2, kq = tid & 3;
    u32 pk[8];
#pragma unroll
    for (int t = 0; t < 8; ++t) {
      u16 lo = f2bf(lds[(kq * 16 + 2 * t) * 65 + l]);
      u16 hi = f2bf(lds[(kq * 16 + 2 * t + 1) * 65 + l]);
      pk[t] = (u32)lo | ((u32)hi << 16);
    }
    u32* dst = (u32*)(wt + (size_t)(l0 + l) * IDIM + k0 + kq * 16);
    ((uint4*)dst)[0] = make_uint4(pk[0], pk[1], pk[2], pk[3]);
    ((uint4*)dst)[1] = make_uint4(pk[4], pk[5], pk[6], pk[7]);
  } else {
    int b = blk - PREPX_BLKS - PREPW_BLKS;
    if (b < 256) {
      float s = 0.f;
#pragma unroll
      for (int j = tid; j < IDIM; j += 256) {
        float v = mu[(size_t)b * IDIM + j];
        wt[(size_t)(NLIT + b) * IDIM + j] = f2bf(v);
        s += v * v;
      }
      float* red = lds;
      red[tid] = s;
      __syncthreads();
      for (int sh = 128; sh > 0; sh >>= 1) {
        if (tid < sh) red[tid] += red[tid + sh];
        __syncthreads();
      }
      if (tid == 0) musq[b] = red[0];
    } else {
      int row = NLIT + 256 + (b - 256);  // 11008..11135
      for (int j = tid; j < IDIM; j += 256) wt[(size_t)row * IDIM + j] = 0;
    }
  }
}

// ---------------- main fused GEMM (R4 double-buffered core) ----------------

__global__ __launch_bounds__(256, 2) void dnnf_gemm(
    const u16* __restrict__ xb, const u16* __restrict__ wt,
    const float* __restrict__ bias, float* __restrict__ form_sum,
    float* __restrict__ dotbuf) {
  __shared__ __align__(16) char smraw[2 * BUFB];  // 81920 B -> 2 blocks/CU

  const int tid = threadIdx.x;
  const int wave = tid >> 6, lane = tid & 63;
  const int wm = wave & 1, wn = wave >> 1;
  // R4 grid: x = n (58), y = m (64)
  const int m0 = blockIdx.y * BM, n0 = blockIdx.x * BN;
  const int q = lane >> 4, cn = lane & 15;

  // staging: chunk c = tid + i*256, r = c>>3, kg = (c&7) ^ (r&7)
  const int kg8 = ((tid & 7) ^ ((tid >> 3) & 7)) * 8;
  const u16* pa = xb + (size_t)(m0 + (tid >> 3)) * IDIM + kg8;
  const u16* pb = wt + (size_t)(n0 + (tid >> 3)) * IDIM + kg8;
  const int dA = tid * 16;          // + i*4096, i<4
  const int dB = 16384 + tid * 16;  // + i*4096, i<6

  const int kg0_16 = ((q ^ (cn & 7)) << 4);
  int offA[4], offB[6];
#pragma unroll
  for (int mf = 0; mf < 4; ++mf)
    offA[mf] = (wm * 64 + mf * 16 + cn) * 128 + kg0_16;
#pragma unroll
  for (int nf = 0; nf < 6; ++nf)
    offB[nf] = 16384 + (wn * 96 + nf * 16 + cn) * 128 + kg0_16;

  f32x4 acc[4][6];
#pragma unroll
  for (int a = 0; a < 4; ++a)
#pragma unroll
    for (int b = 0; b < 6; ++b) acc[a][b] = (f32x4){0.f, 0.f, 0.f, 0.f};

  // prologue: tile 0 -> buffer 0
#pragma unroll
  for (int i = 0; i < 4; ++i)
    async_cp16(pa + (size_t)i * 32 * IDIM, smraw + dA + i * 4096);
#pragma unroll
  for (int i = 0; i < 6; ++i)
    async_cp16(pb + (size_t)i * 32 * IDIM, smraw + dB + i * 4096);
  pa += BK;
  pb += BK;

#pragma unroll
  for (int kt = 0; kt < 8; ++kt) {
    const char* bufc = smraw + (kt & 1) * BUFB;
    if (kt < 7) {
      char* bufn = smraw + ((kt + 1) & 1) * BUFB;
#pragma unroll
      for (int i = 0; i < 4; ++i)
        async_cp16(pa + (size_t)i * 32 * IDIM, bufn + dA + i * 4096);
#pragma unroll
      for (int i = 0; i < 6; ++i)
        async_cp16(pb + (size_t)i * 32 * IDIM, bufn + dB + i * 4096);
      pa += BK;
      pb += BK;
      asm volatile("s_waitcnt vmcnt(10)\n\ts_barrier" ::: "memory");
    } else {
      asm volatile("s_waitcnt vmcnt(0)\n\ts_barrier" ::: "memory");
    }
#pragma unroll
    for (int ks = 0; ks < 2; ++ks) {
      const int x64 = ks ? 64 : 0;
      bf16x8 af[4], bfr[6];
#pragma unroll
      for (int mf = 0; mf < 4; ++mf)
        af[mf] = *(const bf16x8*)(bufc + (offA[mf] ^ x64));
#pragma unroll
      for (int nf = 0; nf < 6; ++nf)
        bfr[nf] = *(const bf16x8*)(bufc + (offB[nf] ^ x64));
#pragma unroll
      for (int mf = 0; mf < 4; ++mf)
#pragma unroll
        for (int nf = 0; nf < 6; ++nf)
          acc[mf][nf] = __builtin_amdgcn_mfma_f32_16x16x32_bf16(
              af[mf], bfr[nf], acc[mf][nf], 0, 0, 0);
    }
    if (kt < 7)
      asm volatile("s_waitcnt lgkmcnt(0)\n\ts_barrier" ::: "memory");
  }
  __syncthreads();  // all waves done with staging LDS before slit reuse

  if (n0 < NLIT) {
    // ---- wave-local epilogue: NO further barriers ----
    // per-wave region: [96 cols][PADU u32], u32 packs rows (2rp, 2rp+1) bf16
    u32* wbase = (u32*)smraw + wave * 96 * PADU;

    // write: 24 x ds_write_b64 per thread
#pragma unroll
    for (int nf = 0; nf < 6; ++nf) {
      float bv = bias[n0 + wn * 96 + nf * 16 + cn];
      int col = nf * 16 + cn;
#pragma unroll
      for (int mf = 0; mf < 4; ++mf) {
        float t0 = fast_tanh(acc[mf][nf][0] + bv);
        float t1 = fast_tanh(acc[mf][nf][1] + bv);
        float t2 = fast_tanh(acc[mf][nf][2] + bv);
        float t3 = fast_tanh(acc[mf][nf][3] + bv);
        uint2 pk;
        pk.x = (u32)f2bf(t0) | ((u32)f2bf(t1) << 16);
        pk.y = (u32)f2bf(t2) | ((u32)f2bf(t3) << 16);
        // rows q*4+0..3 -> row-pairs q*2, q*2+1; slot = col*PADU + mf*8 + q*2
        *(uint2*)(wbase + col * PADU + mf * 8 + q * 2) = pk;
      }
    }

    // read: lane handles row-pair rp = lane>>1, col half = lane&1 (48 cols)
    int rp = lane >> 1, half = lane & 1;
    const u32* src = wbase + half * 48 * PADU + rp;
    int gr = m0 + wm * 64 + rp * 2;
    float* fs0 = form_sum + (size_t)gr * NFORM;
    float* fs1 = fs0 + NFORM;
    int cbase = ((n0 + wn * 96 + half * 48) / 12) * 3;
    float run0 = 0.f, run1 = 0.f;
    int fprev = -1;
#define LOF(u) __uint_as_float((u) << 16)
#define HIF(u) __uint_as_float((u) & 0xffff0000u)
#pragma unroll
    for (int tr = 0; tr < 4; ++tr) {
      const u32* p = src + tr * 12 * PADU;
      u32 a0 = p[0], a1 = p[PADU], a2 = p[2 * PADU], a3 = p[3 * PADU];
      u32 a4 = p[4 * PADU], a5 = p[5 * PADU], a6 = p[6 * PADU];
      u32 a7 = p[7 * PADU], a8 = p[8 * PADU], a9 = p[9 * PADU];
      u32 a10 = p[10 * PADU], a11 = p[11 * PADU];
      float s2l = LOF(a0) + LOF(a1);
      float s2h = HIF(a0) + HIF(a1);
      float s4l = LOF(a2) + LOF(a3) + LOF(a4) + LOF(a5);
      float s4h = HIF(a2) + HIF(a3) + HIF(a4) + HIF(a5);
      float s6l = LOF(a6) + LOF(a7) + LOF(a8) + LOF(a9) + LOF(a10) + LOF(a11);
      float s6h = HIF(a6) + HIF(a7) + HIF(a8) + HIF(a9) + HIF(a10) + HIF(a11);
      float v0 = fast_tanh(s2l - 0.5f) + fast_tanh(s4l - 2.5f) +
                 fast_tanh(s6l - 4.5f);
      float v1 = fast_tanh(s2h - 0.5f) + fast_tanh(s4h - 2.5f) +
                 fast_tanh(s6h - 4.5f);
      int c = cbase + tr * 3;
      int f = (c < 384)    ? (c / 6)
              : (c < 960)  ? 64 + (c - 384) / 9
              : (c < 1728) ? 128 + (c - 960) / 12
                           : 192 + (c - 1728) / 15;
      if (f != fprev) {
        if (fprev >= 0) {
          atomicAdd(fs0 + fprev, run0);
          atomicAdd(fs1 + fprev, run1);
        }
        fprev = f;
        run0 = 0.f;
        run1 = 0.f;
      }
      run0 += v0;
      run1 += v1;
    }
    atomicAdd(fs0 + fprev, run0);
    atomicAdd(fs1 + fprev, run1);
#undef LOF
#undef HIF
  } else {
    // mu tiles: store raw x.mu dots
#pragma unroll
    for (int nf = 0; nf < 6; ++nf) {
      int col = n0 - NLIT + wn * 96 + nf * 16 + cn;
      if (col < NFORM) {
#pragma unroll
        for (int mf = 0; mf < 4; ++mf)
#pragma unroll
          for (int reg = 0; reg < 4; ++reg) {
            int row = wm * 64 + mf * 16 + q * 4 + reg;
            dotbuf[(size_t)(m0 + row) * NFORM + col] = acc[mf][nf][reg];
          }
      }
    }
  }
}

// ---------------- finale: RBF softmax * dnnf (wave-per-row) ----------------

__global__ __launch_bounds__(256) void finale(
    const float* __restrict__ form_sum, const float* __restrict__ dotbuf,
    const float* __restrict__ xsq, const float* __restrict__ musq,
    const float* __restrict__ sigma, float* __restrict__ out) {
  int wave = threadIdx.x >> 6, lane = threadIdx.x & 63;
  int r = blockIdx.x * 4 + wave;
  size_t base = (size_t)r * NFORM;
  float xs = xsq[r];
  float e[4], s = 0.f;
#pragma unroll
  for (int j = 0; j < 4; ++j) {
    int f = j * 64 + lane;
    float sq = xs - 2.0f * dotbuf[base + f] + musq[f];
    float sg = sigma[f];
    float p = __expf(-0.5f * sq / (sg * sg));
    e[j] = __expf(2.0f * p);  // TEMPERATURE=2; values in [1, e^2]
    s += e[j];
  }
#pragma unroll
  for (int o = 32; o > 0; o >>= 1) s += __shfl_xor(s, o);
  float inv = __builtin_amdgcn_rcpf(s);
#pragma unroll
  for (int j = 0; j < 4; ++j) {
    int f = j * 64 + lane;
    float dn = fast_tanh(form_sum[base + f] + (float)(6 + 3 * j) - 1.5f);
    out[base + f] = dn * e[j] * inv;
  }
}

// ---------------- launch ----------------

extern "C" void kernel_launch(void* const* d_in, const int* in_sizes, int n_in,
                              void* d_out, int out_size, void* d_ws,
                              size_t ws_size, hipStream_t stream) {
  const float* x = (const float*)d_in[0];
  const float* W = (const float*)d_in[1];
  const float* M = (const float*)d_in[2];
  const float* bias = (const float*)d_in[3];
  const float* mu = (const float*)d_in[4];
  const float* sigma = (const float*)d_in[5];
  float* out = (float*)d_out;

  float* form_sum = (float*)d_ws;                       // 8 MB
  float* dotbuf = form_sum + (size_t)BATCH * NFORM;     // 8 MB
  u16* xb = (u16*)(dotbuf + (size_t)BATCH * NFORM);     // 8 MB
  u16* wt = xb + (size_t)BATCH * IDIM;                  // 11.4 MB
  float* xsq = (float*)(wt + (size_t)WT_ROWS * IDIM);   // 32 KB
  float* musq = xsq + BATCH;                            // 1 KB

  prep_all<<<PREPX_BLKS + PREPW_BLKS + 384, 256, 0, stream>>>(
      x, W, M, mu, xb, wt, xsq, musq, form_sum);
  // R4 grid: x = n (58), y = m (64)
  dnnf_gemm<<<dim3(WT_ROWS / BN, BATCH / BM), 256, 0, stream>>>(xb, wt, bias,
                                                                form_sum, dotbuf);
  finale<<<BATCH / 4, 256, 0, stream>>>(form_sum, dotbuf, xsq, musq, sigma, out);
}